// Round 3
// baseline (2898.271 us; speedup 1.0000x reference)
//
#include <hip/hip_runtime.h>

#define IMG     512
#define WIN     11
#define CH      48             // output rows per block (multiple of 12)
#define NCHUNK  11             // ceil(512/48)
#define NT      512
#define RPITCH  528            // dwords per ring row: 8 pad + 512 + 8 pad
#define FPLANE  (4*RPITCH)     // ring depth 4 -> 2112 dwords per field
#define RING_DW (5*FPLANE)     // 10560 dwords = 42.24 KB

// ---------------------------------------------------------------------------
// Fused streaming SSIM: block = 512 cols x 48 output rows of one plane.
// Vertical 11-tap in registers (12 rotating slots x 5 fields, static-indexed
// via 3-phase x 4-row unroll), flush to a depth-4 LDS ring, horizontal 11-tap
// via aligned ds_read_b128, SSIM map + per-block partial sum.
// ---------------------------------------------------------------------------
__global__ __launch_bounds__(NT, 4)
void ssim_fused(const float* __restrict__ x,
                const float* __restrict__ y,
                const float* __restrict__ kern,
                float* __restrict__ partial)
{
    __shared__ float ring[RING_DW];
    __shared__ float wsum[NT/64];

    const int tid   = threadIdx.x;
    const int plane = blockIdx.x / NCHUNK;
    const int chunk = blockIdx.x - plane * NCHUNK;
    const int r0    = chunk * CH;                  // r0 % 12 == 0
    const int oMax  = min(r0 + CH - 1, IMG - 1);

    const float* xp = x + (size_t)plane * (IMG*IMG);
    const float* yp = y + (size_t)plane * (IMG*IMG);

    // 1D separable weights: w[i] = k2[i][5] / sqrt(k2[5][5])
    float w[WIN];
    {
        const float cinv = rsqrtf(kern[5*WIN+5]);
        #pragma unroll
        for (int i = 0; i < WIN; ++i) w[i] = kern[i*WIN+5] * cinv;
    }

    // zero ring (pads never rewritten -> stay zero)
    for (int idx = tid; idx < RING_DW; idx += NT) ring[idx] = 0.f;

    // 12 rotating vertical accumulators x 5 fields (all static-indexed)
    float aX[12], aY[12], aXX[12], aYY[12], aXY[12];
    #pragma unroll
    for (int s = 0; s < 12; ++s) { aX[s]=0.f; aY[s]=0.f; aXX[s]=0.f; aYY[s]=0.f; aXY[s]=0.f; }

    float lsum = 0.f;
    const int i0  = r0 - 12;       // 12-aligned phase origin
    const int iLo = r0 - 5;        // first useful input row
    const int iHi = r0 + 52;       // last useful input row (may exceed 511)

    __syncthreads();

    for (int S = 0; S < 6; ++S) {
        #pragma unroll
        for (int q = 0; q < 3; ++q) {
            const int ibase = i0 + 12*S + 4*q;

            // ---- vertical phase: 4 input rows ----
            #pragma unroll
            for (int m = 0; m < 4; ++m) {
                const int i    = ibase + m;
                const int imod = 4*q + m;            // == i mod 12 (compile-time)

                if (i >= iLo && i <= iHi && i >= 0 && i < IMG) {   // uniform branch
                    const float vx  = xp[(size_t)i*IMG + tid];
                    const float vy  = yp[(size_t)i*IMG + tid];
                    const float vxx = vx*vx, vyy = vy*vy, vxy = vx*vy;
                    #pragma unroll
                    for (int s = 0; s < 12; ++s) {
                        const int km = (imod + 17 - s) % 12;        // tap index
                        if (km < 11) {
                            const float wk = w[km];
                            aX [s] += wk * vx;
                            aY [s] += wk * vy;
                            aXX[s] += wk * vxx;
                            aYY[s] += wk * vyy;
                            aXY[s] += wk * vxy;
                        }
                    }
                }

                // flush completed output row o = i-5 (slot sF), then reset
                const int sF = (imod + 7) % 12;                     // compile-time
                const int o  = i - 5;
                if (o >= r0 && o <= oMax) {                         // uniform branch
                    const int dw = ((m + 3) & 3) * RPITCH + 8 + tid; // slot = o%4
                    ring[0*FPLANE + dw] = aX [sF];
                    ring[1*FPLANE + dw] = aY [sF];
                    ring[2*FPLANE + dw] = aXX[sF];
                    ring[3*FPLANE + dw] = aYY[sF];
                    ring[4*FPLANE + dw] = aXY[sF];
                }
                aX[sF]=0.f; aY[sF]=0.f; aXX[sF]=0.f; aYY[sF]=0.f; aXY[sF]=0.f;
            }

            __syncthreads();

            // ---- horizontal phase: the <=4 rows completed this phase ----
            {
                const int rr   = tid >> 7;       // 0..3  (wave-uniform)
                const int quad = tid & 127;      // output cols 4*quad .. +3
                const int oh   = ibase - 5 + rr;
                if (oh >= r0 && oh <= oMax) {
                    const int slot = (rr + 3) & 3;       // == oh % 4
                    float res[5][4];
                    #pragma unroll
                    for (int f = 0; f < 5; ++f)
                        #pragma unroll
                        for (int j = 0; j < 4; ++j) res[f][j] = 0.f;

                    #pragma unroll
                    for (int f = 0; f < 5; ++f) {
                        const int base = f*FPLANE + slot*RPITCH + 4*quad;
                        #pragma unroll
                        for (int n = 0; n < 5; ++n) {    // 5 aligned b128 reads
                            const float4 qv = *reinterpret_cast<const float4*>(&ring[base + 4*n]);
                            const float qe[4] = {qv.x, qv.y, qv.z, qv.w};
                            #pragma unroll
                            for (int e = 0; e < 4; ++e) {
                                const int r = 4*n + e;
                                #pragma unroll
                                for (int j = 0; j < 4; ++j) {
                                    const int k = r - j - 3;   // tap index
                                    if (k >= 0 && k < 11)
                                        res[f][j] += w[k] * qe[e];
                                }
                            }
                        }
                    }
                    #pragma unroll
                    for (int j = 0; j < 4; ++j) {
                        const float mx = res[0][j], my = res[1][j];
                        const float mxx = mx*mx, myy = my*my, mxy = mx*my;
                        const float sxx = res[2][j] - mxx;
                        const float syy = res[3][j] - myy;
                        const float sxy = res[4][j] - mxy;
                        const float num = (2.f*mxy + 1e-4f) * (2.f*sxy + 9e-4f);
                        const float den = (mxx + myy + 1e-4f) * (sxx + syy + 9e-4f);
                        lsum += num * __builtin_amdgcn_rcpf(den);
                    }
                }
            }

            __syncthreads();   // ring slots reused next phase
        }
    }

    // ---- block reduction -> one partial per block ----
    #pragma unroll
    for (int off = 32; off > 0; off >>= 1)
        lsum += __shfl_down(lsum, off, 64);
    if ((tid & 63) == 0) wsum[tid >> 6] = lsum;
    __syncthreads();
    if (tid == 0) {
        float s = 0.f;
        #pragma unroll
        for (int k = 0; k < NT/64; ++k) s += wsum[k];
        partial[blockIdx.x] = s;
    }
}

__global__ __launch_bounds__(NT)
void ssim_finalize(const float* __restrict__ partial, int n,
                   float* __restrict__ out, float invN)
{
    __shared__ float wsum[NT/64];
    float s = 0.f;
    for (int i = threadIdx.x; i < n; i += NT) s += partial[i];
    #pragma unroll
    for (int off = 32; off > 0; off >>= 1)
        s += __shfl_down(s, off, 64);
    if ((threadIdx.x & 63) == 0) wsum[threadIdx.x >> 6] = s;
    __syncthreads();
    if (threadIdx.x == 0) {
        float t = 0.f;
        #pragma unroll
        for (int k = 0; k < NT/64; ++k) t += wsum[k];
        out[0] = 1.0f - t * invN;
    }
}

extern "C" void kernel_launch(void* const* d_in, const int* in_sizes, int n_in,
                              void* d_out, int out_size, void* d_ws, size_t ws_size,
                              hipStream_t stream)
{
    const float* x    = (const float*)d_in[0];
    const float* y    = (const float*)d_in[1];
    const float* kern = (const float*)d_in[2];
    float* out     = (float*)d_out;
    float* partial = (float*)d_ws;

    const int planes  = in_sizes[0] / (IMG*IMG);    // B*C = 64
    const int nBlocks = planes * NCHUNK;            // 704

    ssim_fused<<<nBlocks, NT, 0, stream>>>(x, y, kern, partial);
    ssim_finalize<<<1, NT, 0, stream>>>(partial, nBlocks, out,
                                        1.0f / ((float)planes * IMG * IMG));
}

// Round 4
// 402.274 us; speedup vs baseline: 7.2047x; 7.2047x over previous
//
#include <hip/hip_runtime.h>

#define IMG   512
#define WIN   11
#define TW    64              // tile width  (output cols)
#define TH    32              // tile height (output rows)
#define HR    (TH + WIN - 1)  // 42 h-filtered rows
#define HP    68              // hbuf row pitch (dwords), 16B-aligned rows
#define FPL   (HR * HP)       // 2856 dwords per field
#define NT    256

// guarded float4 load of cols c..c+3 from one image row (zero outside)
__device__ __forceinline__ float4 loadg4(const float* __restrict__ rowp,
                                         int c, bool rowok) {
    float4 v = make_float4(0.f, 0.f, 0.f, 0.f);
    if (rowok) {
        if ((unsigned)c <= (unsigned)(IMG - 4)) {
            v = *reinterpret_cast<const float4*>(rowp + c);
        } else {
            if ((unsigned)(c + 0) < IMG) v.x = rowp[c + 0];
            if ((unsigned)(c + 1) < IMG) v.y = rowp[c + 1];
            if ((unsigned)(c + 2) < IMG) v.z = rowp[c + 2];
            if ((unsigned)(c + 3) < IMG) v.w = rowp[c + 3];
        }
    }
    return v;
}

__device__ __forceinline__ float ssim_pt(float mx, float my, float fss, float fxy) {
    const float t   = fmaf(my, my, mx * mx);    // mx^2 + my^2
    const float mxy = mx * my;
    const float sig = fss - t;                  // sxx + syy
    const float sxy = fxy - mxy;
    const float num = fmaf(2.f, mxy, 1e-4f) * fmaf(2.f, sxy, 9e-4f);
    const float den = (t + 1e-4f) * (sig + 9e-4f);
    return num * __builtin_amdgcn_rcpf(den);
}

// ---------------------------------------------------------------------------
// One block = 64x32 output tile. h-phase: 11-tap horizontal conv of 4 fields
// (x, y, x^2+y^2, x*y) straight from global (register window, float4 loads),
// results to LDS as float4. v-phase: 11-tap vertical conv via ds_read_b128,
// SSIM map, block sum, global atomic + counter-based single-kernel finalize.
// ---------------------------------------------------------------------------
__global__ __launch_bounds__(NT, 3)
void ssim_fused(const float* __restrict__ x,
                const float* __restrict__ y,
                const float* __restrict__ kern,
                float* __restrict__ accum,
                int*   __restrict__ counter,
                float* __restrict__ out,
                float invN, int nBlocks)
{
    __shared__ float hbuf[4 * FPL];     // 45,696 B
    __shared__ float wsum[NT / 64];

    const int tid   = threadIdx.x;
    const int bid   = blockIdx.x;
    const int plane = bid >> 7;                 // 128 tiles per plane
    const int rem   = bid & 127;
    const int row0  = (rem >> 3) * TH;          // 16 tile-rows
    const int col0  = (rem & 7)  * TW;          // 8 tile-cols

    const float* __restrict__ xp = x + (size_t)plane * (IMG * IMG);
    const float* __restrict__ yp = y + (size_t)plane * (IMG * IMG);

    // 1D separable weights: w[i] = k2[i][5] / sqrt(k2[5][5])
    float w[WIN];
    {
        const float cinv = rsqrtf(kern[5 * WIN + 5]);
        #pragma unroll
        for (int i = 0; i < WIN; ++i) w[i] = kern[i * WIN + 5] * cinv;
    }

    // ---- h-phase: 42 rows x 16 quads, 4 outputs/task ----
    for (int task = tid; task < HR * 16; task += NT) {
        const int r  = task >> 4;              // 0..41
        const int q  = task & 15;
        const int gr = row0 - 5 + r;
        const bool rok = (unsigned)gr < IMG;
        const float* xr = xp + (size_t)gr * IMG;
        const float* yr = yp + (size_t)gr * IMG;

        float sx[20], sy[20], ss[20];
        #pragma unroll
        for (int jj = 0; jj < 5; ++jj) {
            const int c = col0 + 4 * q - 8 + 4 * jj;
            const float4 vx = loadg4(xr, c, rok);
            const float4 vy = loadg4(yr, c, rok);
            sx[4*jj+0] = vx.x; sx[4*jj+1] = vx.y; sx[4*jj+2] = vx.z; sx[4*jj+3] = vx.w;
            sy[4*jj+0] = vy.x; sy[4*jj+1] = vy.y; sy[4*jj+2] = vy.z; sy[4*jj+3] = vy.w;
            ss[4*jj+0] = fmaf(vy.x, vy.x, vx.x * vx.x);
            ss[4*jj+1] = fmaf(vy.y, vy.y, vx.y * vx.y);
            ss[4*jj+2] = fmaf(vy.z, vy.z, vx.z * vx.z);
            ss[4*jj+3] = fmaf(vy.w, vy.w, vx.w * vx.w);
        }

        float hx[4]  = {0.f, 0.f, 0.f, 0.f};
        float hy[4]  = {0.f, 0.f, 0.f, 0.f};
        float hs[4]  = {0.f, 0.f, 0.f, 0.f};
        float hxy[4] = {0.f, 0.f, 0.f, 0.f};
        #pragma unroll
        for (int k = 0; k < WIN; ++k) {
            const float wk = w[k];
            #pragma unroll
            for (int j = 0; j < 4; ++j) {
                const int idx = j + k + 3;          // 3..16, compile-time
                hx[j]  = fmaf(wk, sx[idx], hx[j]);
                hy[j]  = fmaf(wk, sy[idx], hy[j]);
                hs[j]  = fmaf(wk, ss[idx], hs[j]);
                hxy[j] = fmaf(wk, sx[idx] * sy[idx], hxy[j]);
            }
        }

        const int b = r * HP + 4 * q;
        *reinterpret_cast<float4*>(&hbuf[0*FPL + b]) = make_float4(hx[0],  hx[1],  hx[2],  hx[3]);
        *reinterpret_cast<float4*>(&hbuf[1*FPL + b]) = make_float4(hy[0],  hy[1],  hy[2],  hy[3]);
        *reinterpret_cast<float4*>(&hbuf[2*FPL + b]) = make_float4(hs[0],  hs[1],  hs[2],  hs[3]);
        *reinterpret_cast<float4*>(&hbuf[3*FPL + b]) = make_float4(hxy[0], hxy[1], hxy[2], hxy[3]);
    }

    __syncthreads();

    // ---- v-phase: thread -> float4 col-quad q, output rows 2g, 2g+1 ----
    float lsum = 0.f;
    {
        const int q = tid & 15;
        const int g = tid >> 4;                 // 0..15
        float4 aX[2], aY[2], aS[2], aP[2];
        #pragma unroll
        for (int j = 0; j < 2; ++j) {
            aX[j] = make_float4(0,0,0,0); aY[j] = make_float4(0,0,0,0);
            aS[j] = make_float4(0,0,0,0); aP[j] = make_float4(0,0,0,0);
        }

        #pragma unroll
        for (int t = 0; t < 12; ++t) {
            const int b = (2 * g + t) * HP + 4 * q;
            const float4 vX = *reinterpret_cast<const float4*>(&hbuf[0*FPL + b]);
            const float4 vY = *reinterpret_cast<const float4*>(&hbuf[1*FPL + b]);
            const float4 vS = *reinterpret_cast<const float4*>(&hbuf[2*FPL + b]);
            const float4 vP = *reinterpret_cast<const float4*>(&hbuf[3*FPL + b]);
            #pragma unroll
            for (int j = 0; j < 2; ++j) {
                const int k = t - j;                 // tap index, compile-time
                if (k >= 0 && k < WIN) {
                    const float wk = w[k];
                    aX[j].x = fmaf(wk, vX.x, aX[j].x); aX[j].y = fmaf(wk, vX.y, aX[j].y);
                    aX[j].z = fmaf(wk, vX.z, aX[j].z); aX[j].w = fmaf(wk, vX.w, aX[j].w);
                    aY[j].x = fmaf(wk, vY.x, aY[j].x); aY[j].y = fmaf(wk, vY.y, aY[j].y);
                    aY[j].z = fmaf(wk, vY.z, aY[j].z); aY[j].w = fmaf(wk, vY.w, aY[j].w);
                    aS[j].x = fmaf(wk, vS.x, aS[j].x); aS[j].y = fmaf(wk, vS.y, aS[j].y);
                    aS[j].z = fmaf(wk, vS.z, aS[j].z); aS[j].w = fmaf(wk, vS.w, aS[j].w);
                    aP[j].x = fmaf(wk, vP.x, aP[j].x); aP[j].y = fmaf(wk, vP.y, aP[j].y);
                    aP[j].z = fmaf(wk, vP.z, aP[j].z); aP[j].w = fmaf(wk, vP.w, aP[j].w);
                }
            }
        }

        #pragma unroll
        for (int j = 0; j < 2; ++j) {
            lsum += ssim_pt(aX[j].x, aY[j].x, aS[j].x, aP[j].x);
            lsum += ssim_pt(aX[j].y, aY[j].y, aS[j].y, aP[j].y);
            lsum += ssim_pt(aX[j].z, aY[j].z, aS[j].z, aP[j].z);
            lsum += ssim_pt(aX[j].w, aY[j].w, aS[j].w, aP[j].w);
        }
    }

    // ---- block reduction -> one atomic, counter-based finalize ----
    #pragma unroll
    for (int off = 32; off > 0; off >>= 1)
        lsum += __shfl_down(lsum, off, 64);
    if ((tid & 63) == 0) wsum[tid >> 6] = lsum;
    __syncthreads();
    if (tid == 0) {
        const float s = wsum[0] + wsum[1] + wsum[2] + wsum[3];
        atomicAdd(accum, s);
        __threadfence();
        const int old = atomicAdd(counter, 1);
        if (old == nBlocks - 1) {
            const float tot = atomicAdd(accum, 0.0f);   // coherent read
            out[0] = 1.0f - tot * invN;
        }
    }
}

extern "C" void kernel_launch(void* const* d_in, const int* in_sizes, int n_in,
                              void* d_out, int out_size, void* d_ws, size_t ws_size,
                              hipStream_t stream)
{
    const float* x    = (const float*)d_in[0];
    const float* y    = (const float*)d_in[1];
    const float* kern = (const float*)d_in[2];
    float* out     = (float*)d_out;
    float* accum   = (float*)d_ws;
    int*   counter = (int*)d_ws + 1;

    const int planes  = in_sizes[0] / (IMG * IMG);   // B*C = 64
    const int nBlocks = planes * 128;                // 8192

    hipMemsetAsync(d_ws, 0, 2 * sizeof(float), stream);
    ssim_fused<<<nBlocks, NT, 0, stream>>>(
        x, y, kern, accum, counter, out,
        1.0f / ((float)planes * IMG * IMG), nBlocks);
}